// Round 4
// baseline (166.535 us; speedup 1.0000x reference)
//
#include <hip/hip_runtime.h>

// Problem constants (B=1, L=2048, E=512, H=8, D=64)
constexpr int L_SEQ = 2048;
constexpr int E_DIM = 512;
constexpr int H_NUM = 8;
constexpr int QKV_W = 3 * E_DIM;   // 1536
constexpr int NC = 32;             // 32 chunks of 64
constexpr float PI_HALF = 1.5707963267948966f;

typedef __attribute__((ext_vector_type(8))) short bf16x8;
typedef __attribute__((ext_vector_type(4))) float f32x4;
typedef __attribute__((ext_vector_type(4))) short short4v;

__device__ __forceinline__ short f2bf(float f) {
  union { float f; unsigned int u; } v; v.f = f;
  unsigned int r = v.u + 0x7fffu + ((v.u >> 16) & 1u);  // RNE
  return (short)(r >> 16);
}
__device__ __forceinline__ float bf2f(short s) {
  union { unsigned int u; float f; } v;
  v.u = ((unsigned int)(unsigned short)s) << 16;
  return v.f;
}

__device__ __forceinline__ void glds16(const void* g, void* l) {
  __builtin_amdgcn_global_load_lds(
      (const __attribute__((address_space(1))) unsigned int*)g,
      (__attribute__((address_space(3))) unsigned int*)l, 16, 0, 0);
}

// ---------------------------------------------------------------------------
// bf16 MFMA GEMM: C[M,N] = A[M,K](bf16) @ Bt[N,K](bf16)^T + bias[N]
// OB=true -> C bf16, else C fp32. 256 threads = 4 waves (2x2).
// ---------------------------------------------------------------------------
template <int WTM, int WTN, bool OB>
__global__ __launch_bounds__(256) void gemm_mfma_bf16(
    const short* __restrict__ A, const short* __restrict__ Bt,
    const float* __restrict__ bias, void* __restrict__ Cout,
    int M, int N, int K) {
  constexpr int BM = WTM * 32;
  constexpr int BN = WTN * 32;
  __shared__ short As[BM * 32];
  __shared__ short Bs[BN * 32];

  const int t = threadIdx.x;
  const int wave = t >> 6;
  const int lane = t & 63;
  const int quad = lane >> 4;
  const int lr = lane & 15;

  const int row0 = blockIdx.y * BM;
  const int col0 = blockIdx.x * BN;
  const int wrow = (wave >> 1) * (BM / 2);
  const int wcol = (wave & 1) * (BN / 2);

  f32x4 acc[WTM][WTN];
#pragma unroll
  for (int m = 0; m < WTM; ++m)
#pragma unroll
    for (int n = 0; n < WTN; ++n) acc[m][n] = (f32x4){0.f, 0.f, 0.f, 0.f};

  for (int k0 = 0; k0 < K; k0 += 32) {
#pragma unroll
    for (int p = wave; p < BM / 16; p += 4) {
      const int idx = p * 64 + lane;
      glds16(A + (size_t)(row0 + (idx >> 2)) * K + k0 + (idx & 3) * 8, As + p * 512);
    }
#pragma unroll
    for (int p = wave; p < BN / 16; p += 4) {
      const int idx = p * 64 + lane;
      glds16(Bt + (size_t)(col0 + (idx >> 2)) * K + k0 + (idx & 3) * 8, Bs + p * 512);
    }
    __syncthreads();

    bf16x8 af[WTM], bf_[WTN];
#pragma unroll
    for (int m = 0; m < WTM; ++m)
      af[m] = *(const bf16x8*)(As + (wrow + m * 16 + lr) * 32 + quad * 8);
#pragma unroll
    for (int n = 0; n < WTN; ++n)
      bf_[n] = *(const bf16x8*)(Bs + (wcol + n * 16 + lr) * 32 + quad * 8);
#pragma unroll
    for (int m = 0; m < WTM; ++m)
#pragma unroll
      for (int n = 0; n < WTN; ++n)
        acc[m][n] = __builtin_amdgcn_mfma_f32_16x16x32_bf16(af[m], bf_[n], acc[m][n], 0, 0, 0);
    __syncthreads();
  }

#pragma unroll
  for (int m = 0; m < WTM; ++m) {
#pragma unroll
    for (int n = 0; n < WTN; ++n) {
      const int col = col0 + wcol + n * 16 + lr;
      const int rowb = row0 + wrow + m * 16 + quad * 4;
      const float bb = bias[col];
#pragma unroll
      for (int r = 0; r < 4; ++r) {
        const float val = acc[m][n][r] + bb;
        if (OB)
          ((short*)Cout)[(size_t)(rowb + r) * N + col] = f2bf(val);
        else
          ((float*)Cout)[(size_t)(rowb + r) * N + col] = val;
      }
    }
  }
}

// ---------------------------------------------------------------------------
// Fused prep: cast x -> bf16; transpose-cast W_qkv, W_out -> [N,K] bf16.
// Grid: 1024 cast blocks + 768 Wqkv tiles + 256 Wout tiles = 2048 blocks.
// ---------------------------------------------------------------------------
__global__ __launch_bounds__(256) void prep_kernel(
    const float* __restrict__ x, const float* __restrict__ W_qkv,
    const float* __restrict__ W_out, short* __restrict__ xb,
    short* __restrict__ Wqkv_t, short* __restrict__ Wout_t) {
  const int b = blockIdx.x;
  if (b < 1024) {
    const int i = b * 256 + threadIdx.x;
    const float4 v = ((const float4*)x)[i];
    short4v o;
    o.x = f2bf(v.x); o.y = f2bf(v.y); o.z = f2bf(v.z); o.w = f2bf(v.w);
    ((short4v*)xb)[i] = o;
    return;
  }
  __shared__ float tile[32][33];
  const float* W; short* Wt; int R, Cc, c0, r0;
  if (b < 1792) {
    const int bb = b - 1024;
    W = W_qkv; Wt = Wqkv_t; R = E_DIM; Cc = QKV_W;
    c0 = (bb % 48) * 32; r0 = (bb / 48) * 32;
  } else {
    const int bb = b - 1792;
    W = W_out; Wt = Wout_t; R = E_DIM; Cc = E_DIM;
    c0 = (bb % 16) * 32; r0 = (bb / 16) * 32;
  }
  const int tx = threadIdx.x & 31, ty = threadIdx.x >> 5;
  for (int i = ty; i < 32; i += 8) tile[i][tx] = W[(size_t)(r0 + i) * Cc + c0 + tx];
  __syncthreads();
  for (int i = ty; i < 32; i += 8)
    Wt[(size_t)(c0 + i) * R + r0 + tx] = f2bf(tile[tx][i]);
}

// ---------------------------------------------------------------------------
// Kernel A (MFMA): S_c[(h,c)][e][dd] (bf16) = sum_i v[i][e]*kw[i][dd];
// ksum[(h,c)][dd] (fp32). qkv input is bf16.
// ---------------------------------------------------------------------------
__global__ __launch_bounds__(256) void chunk_kv_mfma(
    const short* __restrict__ qkvb, short* __restrict__ Sb, float* __restrict__ ksum) {
  const int c = blockIdx.x, h = blockIdx.y;
  __shared__ short kT[128][72];  // kw^T [dd][i]
  __shared__ short vT[64][72];   // v^T  [e][i]
  const int t = threadIdx.x;
  const int w = t >> 6, lane = t & 63, lr = lane & 15, quad = lane >> 4;

#pragma unroll
  for (int r = 0; r < 16; ++r) {
    const int i = w + 4 * r, d = lane;
    const short* row = qkvb + (size_t)(c * 64 + i) * QKV_W;
    const float kv_ = fmaxf(bf2f(row[E_DIM + h * 64 + d]), 0.f);
    const float v_ = bf2f(row[2 * E_DIM + h * 64 + d]);
    const float th = PI_HALF * (float)(c * 64 + i) / (float)L_SEQ;
    kT[d][i] = f2bf(kv_ * __cosf(th));
    kT[64 + d][i] = f2bf(kv_ * __sinf(th));
    vT[d][i] = f2bf(v_);
  }
  __syncthreads();

  f32x4 acc[8];
#pragma unroll
  for (int n = 0; n < 8; ++n) acc[n] = (f32x4){0.f, 0.f, 0.f, 0.f};
#pragma unroll
  for (int kk = 0; kk < 2; ++kk) {
    const bf16x8 av = *(const bf16x8*)&vT[16 * w + lr][kk * 32 + quad * 8];
#pragma unroll
    for (int n = 0; n < 8; ++n) {
      const bf16x8 bv = *(const bf16x8*)&kT[16 * n + lr][kk * 32 + quad * 8];
      acc[n] = __builtin_amdgcn_mfma_f32_16x16x32_bf16(av, bv, acc[n], 0, 0, 0);
    }
  }

  short* Sc = Sb + ((size_t)(h * NC + c)) * 8192;  // [e][128]
#pragma unroll
  for (int n = 0; n < 8; ++n) {
    const int dd = 16 * n + lr;
#pragma unroll
    for (int r = 0; r < 4; ++r) {
      const int e = 16 * w + quad * 4 + r;
      Sc[(size_t)e * 128 + dd] = f2bf(acc[n][r]);
    }
  }

  if (t < 128) {
    float s = 0.f;
#pragma unroll
    for (int j = 0; j < 8; ++j) {
      const bf16x8 kv8 = *(const bf16x8*)&kT[t][j * 8];
#pragma unroll
      for (int q = 0; q < 8; ++q) s += bf2f(kv8[q]);
    }
    ksum[(size_t)(h * NC + c) * 128 + t] = s;
  }
}

// ---------------------------------------------------------------------------
// Kernel C (MFMA, fused scan): per-(chunk, head) output -> attn bf16.
//   ctx = sum_{c'<c} Qcat @ S_c'^T  (fp32 MFMA accumulate = exact prefix)
//       + Am @ vT^T                 (intra, causal-masked, weight folded)
//   nrm = rowsum(Am) + Qcat . (sum_{c'<c} ksum_c')
// ---------------------------------------------------------------------------
__global__ __launch_bounds__(256) void chunk_out_fused(
    const short* __restrict__ qkvb, const short* __restrict__ Sb,
    const float* __restrict__ ksum, short* __restrict__ attn) {
  const int c = blockIdx.x, h = blockIdx.y;
  __shared__ short Qc[64][136];
  __shared__ short Kc[64][136];
  __shared__ short Am[64][72];
  __shared__ short vT[64][72];
  __shared__ float ksumP_s[128];
  __shared__ float nrmP[64][4];
  __shared__ float nrmA[64];
  const int t = threadIdx.x;
  const int w = t >> 6, lane = t & 63, lr = lane & 15, quad = lane >> 4;

#pragma unroll
  for (int r = 0; r < 16; ++r) {
    const int i = w + 4 * r, d = lane;
    const short* row = qkvb + (size_t)(c * 64 + i) * QKV_W;
    const float q_ = fmaxf(bf2f(row[h * 64 + d]), 0.f);
    const float k_ = fmaxf(bf2f(row[E_DIM + h * 64 + d]), 0.f);
    const float v_ = bf2f(row[2 * E_DIM + h * 64 + d]);
    const float th = PI_HALF * (float)(c * 64 + i) / (float)L_SEQ;
    const float cw = __cosf(th), sw = __sinf(th);
    Qc[i][d] = f2bf(q_ * cw);
    Qc[i][64 + d] = f2bf(q_ * sw);
    Kc[i][d] = f2bf(k_ * cw);
    Kc[i][64 + d] = f2bf(k_ * sw);
    vT[d][i] = f2bf(v_);
  }
  if (t < 128) {
    float s = 0.f;
    for (int cp = 0; cp < c; ++cp) s += ksum[(size_t)(h * NC + cp) * 128 + t];
    ksumP_s[t] = s;
  }
  __syncthreads();

  // Loop-invariant A-operand fragments of Qcat (row 16w+lr)
  bf16x8 av[4];
#pragma unroll
  for (int kk = 0; kk < 4; ++kk)
    av[kk] = *(const bf16x8*)&Qc[16 * w + lr][kk * 32 + quad * 8];

  // Intra scores: A = Qcat @ Kcat^T
  f32x4 acc_a[4];
#pragma unroll
  for (int n = 0; n < 4; ++n) acc_a[n] = (f32x4){0.f, 0.f, 0.f, 0.f};
#pragma unroll
  for (int kk = 0; kk < 4; ++kk) {
#pragma unroll
    for (int n = 0; n < 4; ++n) {
      const bf16x8 bv = *(const bf16x8*)&Kc[16 * n + lr][kk * 32 + quad * 8];
      acc_a[n] = __builtin_amdgcn_mfma_f32_16x16x32_bf16(av[kk], bv, acc_a[n], 0, 0, 0);
    }
  }
  // Mask, fp32 row-sum via shfl, Am -> LDS bf16
#pragma unroll
  for (int n = 0; n < 4; ++n) {
#pragma unroll
    for (int r = 0; r < 4; ++r) {
      const int gi = 16 * w + quad * 4 + r;
      const int gj = 16 * n + lr;
      float val = (gj <= gi) ? acc_a[n][r] : 0.f;
      Am[gi][gj] = f2bf(val);
      float s = val;
      s += __shfl_xor(s, 1, 64);
      s += __shfl_xor(s, 2, 64);
      s += __shfl_xor(s, 4, 64);
      s += __shfl_xor(s, 8, 64);
      if (lr == 0) nrmP[gi][n] = s;
    }
  }

  // Inter ctx: fused prefix scan in the MFMA accumulator
  f32x4 acc_c[4];
#pragma unroll
  for (int n = 0; n < 4; ++n) acc_c[n] = (f32x4){0.f, 0.f, 0.f, 0.f};
  for (int cp = 0; cp < c; ++cp) {
    const short* Sc = Sb + ((size_t)(h * NC + cp)) * 8192;  // [e][128]
#pragma unroll
    for (int kk = 0; kk < 4; ++kk) {
#pragma unroll
      for (int n = 0; n < 4; ++n) {
        const bf16x8 bv = *(const bf16x8*)(Sc + (size_t)(16 * n + lr) * 128 + kk * 32 + quad * 8);
        acc_c[n] = __builtin_amdgcn_mfma_f32_16x16x32_bf16(av[kk], bv, acc_c[n], 0, 0, 0);
      }
    }
  }
  __syncthreads();  // Am, nrmP, ksumP_s ready

  // Intra ctx: Am @ vT^T
#pragma unroll
  for (int kk = 0; kk < 2; ++kk) {
    const bf16x8 am = *(const bf16x8*)&Am[16 * w + lr][kk * 32 + quad * 8];
#pragma unroll
    for (int n = 0; n < 4; ++n) {
      const bf16x8 bv = *(const bf16x8*)&vT[16 * n + lr][kk * 32 + quad * 8];
      acc_c[n] = __builtin_amdgcn_mfma_f32_16x16x32_bf16(am, bv, acc_c[n], 0, 0, 0);
    }
  }

  // nrm inter-dot: thread (i = t>>2, p = t&3) handles 32 dd
  {
    const int i = t >> 2, p = t & 3;
    float dot = 0.f;
#pragma unroll
    for (int jj = 0; jj < 32; ++jj) {
      const int dd = p * 32 + jj;
      dot += bf2f(Qc[i][dd]) * ksumP_s[dd];
    }
    nrmP[i][p] += dot;
  }
  __syncthreads();
  if (t < 64) nrmA[t] = nrmP[t][0] + nrmP[t][1] + nrmP[t][2] + nrmP[t][3];
  __syncthreads();

#pragma unroll
  for (int n = 0; n < 4; ++n) {
#pragma unroll
    for (int r = 0; r < 4; ++r) {
      const int gi = 16 * w + quad * 4 + r;
      const int e = 16 * n + lr;
      const float val = acc_c[n][r] / (nrmA[gi] + 1e-6f);
      attn[(size_t)(c * 64 + gi) * E_DIM + h * 64 + e] = f2bf(val);
    }
  }
}

// ---------------------------------------------------------------------------
extern "C" void kernel_launch(void* const* d_in, const int* in_sizes, int n_in,
                              void* d_out, int out_size, void* d_ws, size_t ws_size,
                              hipStream_t stream) {
  (void)in_sizes; (void)n_in; (void)out_size; (void)ws_size;
  const float* x     = (const float*)d_in[0];
  const float* W_qkv = (const float*)d_in[1];
  const float* b_qkv = (const float*)d_in[2];
  const float* W_out = (const float*)d_in[3];
  const float* b_out = (const float*)d_in[4];
  float* out = (float*)d_out;

  short* sws = (short*)d_ws;
  short* qkvb   = sws;                     // 3,145,728 bf16
  short* Sb     = qkvb + 3145728;          // 2,097,152 bf16  [hc][e][dd]
  short* attn_b = Sb + 2097152;            // 1,048,576 bf16
  short* xb     = attn_b + 1048576;        // 1,048,576 bf16
  short* Wqkv_t = xb + 1048576;            // 786,432 bf16
  short* Wout_t = Wqkv_t + 786432;         // 262,144 bf16
  float* ksum   = (float*)(Wout_t + 262144);  // 32,768 f32

  // 1) fused prep
  prep_kernel<<<2048, 256, 0, stream>>>(x, W_qkv, W_out, xb, Wqkv_t, Wout_t);

  // 2) qkv = x @ W_qkv + b_qkv -> bf16. 64x64 tiles: 24x32 = 768 blocks (3/CU)
  gemm_mfma_bf16<2, 2, true><<<dim3(QKV_W / 64, L_SEQ / 64), 256, 0, stream>>>(
      xb, Wqkv_t, b_qkv, qkvb, L_SEQ, QKV_W, E_DIM);

  // 3) per-chunk KV sums -> bf16 S, fp32 ksum
  chunk_kv_mfma<<<dim3(NC, H_NUM), 256, 0, stream>>>(qkvb, Sb, ksum);

  // 4) per-chunk outputs with fused prefix scan -> attn bf16
  chunk_out_fused<<<dim3(NC, H_NUM), 256, 0, stream>>>(qkvb, Sb, ksum, attn_b);

  // 5) out = attn @ W_out + b_out -> fp32. 32x64 tiles: 8x64 = 512 blocks (2/CU)
  gemm_mfma_bf16<1, 2, false><<<dim3(E_DIM / 64, L_SEQ / 32), 256, 0, stream>>>(
      attn_b, Wout_t, b_out, out, L_SEQ, E_DIM, E_DIM);
}

// Round 5
// 117.583 us; speedup vs baseline: 1.4163x; 1.4163x over previous
//
#include <hip/hip_runtime.h>

// Problem constants (B=1, L=2048, E=512, H=8, D=64)
constexpr int L_SEQ = 2048;
constexpr int E_DIM = 512;
constexpr int H_NUM = 8;
constexpr int QKV_W = 3 * E_DIM;   // 1536
constexpr int NC = 32;             // 32 chunks of 64
constexpr float PI_HALF = 1.5707963267948966f;

typedef __attribute__((ext_vector_type(8))) short bf16x8;
typedef __attribute__((ext_vector_type(4))) float f32x4;
typedef __attribute__((ext_vector_type(4))) short short4v;

__device__ __forceinline__ short f2bf(float f) {
  union { float f; unsigned int u; } v; v.f = f;
  unsigned int r = v.u + 0x7fffu + ((v.u >> 16) & 1u);  // RNE
  return (short)(r >> 16);
}
__device__ __forceinline__ float bf2f(short s) {
  union { unsigned int u; float f; } v;
  v.u = ((unsigned int)(unsigned short)s) << 16;
  return v.f;
}

__device__ __forceinline__ void glds16(const void* g, void* l) {
  __builtin_amdgcn_global_load_lds(
      (const __attribute__((address_space(1))) unsigned int*)g,
      (__attribute__((address_space(3))) unsigned int*)l, 16, 0, 0);
}

// ---------------------------------------------------------------------------
// bf16 MFMA GEMM: C[M,N] = A[M,K](bf16) @ Bt[N,K](bf16)^T + bias[N]
// OB=true -> C bf16, else C fp32. 256 threads = 4 waves (2x2).
// ---------------------------------------------------------------------------
template <int WTM, int WTN, bool OB>
__global__ __launch_bounds__(256) void gemm_mfma_bf16(
    const short* __restrict__ A, const short* __restrict__ Bt,
    const float* __restrict__ bias, void* __restrict__ Cout,
    int M, int N, int K) {
  constexpr int BM = WTM * 32;
  constexpr int BN = WTN * 32;
  __shared__ short As[BM * 32];
  __shared__ short Bs[BN * 32];

  const int t = threadIdx.x;
  const int wave = t >> 6;
  const int lane = t & 63;
  const int quad = lane >> 4;
  const int lr = lane & 15;

  const int row0 = blockIdx.y * BM;
  const int col0 = blockIdx.x * BN;
  const int wrow = (wave >> 1) * (BM / 2);
  const int wcol = (wave & 1) * (BN / 2);

  f32x4 acc[WTM][WTN];
#pragma unroll
  for (int m = 0; m < WTM; ++m)
#pragma unroll
    for (int n = 0; n < WTN; ++n) acc[m][n] = (f32x4){0.f, 0.f, 0.f, 0.f};

  for (int k0 = 0; k0 < K; k0 += 32) {
#pragma unroll
    for (int p = wave; p < BM / 16; p += 4) {
      const int idx = p * 64 + lane;
      glds16(A + (size_t)(row0 + (idx >> 2)) * K + k0 + (idx & 3) * 8, As + p * 512);
    }
#pragma unroll
    for (int p = wave; p < BN / 16; p += 4) {
      const int idx = p * 64 + lane;
      glds16(Bt + (size_t)(col0 + (idx >> 2)) * K + k0 + (idx & 3) * 8, Bs + p * 512);
    }
    __syncthreads();

    bf16x8 af[WTM], bf_[WTN];
#pragma unroll
    for (int m = 0; m < WTM; ++m)
      af[m] = *(const bf16x8*)(As + (wrow + m * 16 + lr) * 32 + quad * 8);
#pragma unroll
    for (int n = 0; n < WTN; ++n)
      bf_[n] = *(const bf16x8*)(Bs + (wcol + n * 16 + lr) * 32 + quad * 8);
#pragma unroll
    for (int m = 0; m < WTM; ++m)
#pragma unroll
      for (int n = 0; n < WTN; ++n)
        acc[m][n] = __builtin_amdgcn_mfma_f32_16x16x32_bf16(af[m], bf_[n], acc[m][n], 0, 0, 0);
    __syncthreads();
  }

#pragma unroll
  for (int m = 0; m < WTM; ++m) {
#pragma unroll
    for (int n = 0; n < WTN; ++n) {
      const int col = col0 + wcol + n * 16 + lr;
      const int rowb = row0 + wrow + m * 16 + quad * 4;
      const float bb = bias[col];
#pragma unroll
      for (int r = 0; r < 4; ++r) {
        const float val = acc[m][n][r] + bb;
        if (OB)
          ((short*)Cout)[(size_t)(rowb + r) * N + col] = f2bf(val);
        else
          ((float*)Cout)[(size_t)(rowb + r) * N + col] = val;
      }
    }
  }
}

// ---------------------------------------------------------------------------
// Fused prep: cast x -> bf16; transpose-cast W_qkv, W_out -> [N,K] bf16.
// ---------------------------------------------------------------------------
__global__ __launch_bounds__(256) void prep_kernel(
    const float* __restrict__ x, const float* __restrict__ W_qkv,
    const float* __restrict__ W_out, short* __restrict__ xb,
    short* __restrict__ Wqkv_t, short* __restrict__ Wout_t) {
  const int b = blockIdx.x;
  if (b < 1024) {
    const int i = b * 256 + threadIdx.x;
    const float4 v = ((const float4*)x)[i];
    short4v o;
    o.x = f2bf(v.x); o.y = f2bf(v.y); o.z = f2bf(v.z); o.w = f2bf(v.w);
    ((short4v*)xb)[i] = o;
    return;
  }
  __shared__ float tile[32][33];
  const float* W; short* Wt; int R, Cc, c0, r0;
  if (b < 1792) {
    const int bb = b - 1024;
    W = W_qkv; Wt = Wqkv_t; R = E_DIM; Cc = QKV_W;
    c0 = (bb % 48) * 32; r0 = (bb / 48) * 32;
  } else {
    const int bb = b - 1792;
    W = W_out; Wt = Wout_t; R = E_DIM; Cc = E_DIM;
    c0 = (bb % 16) * 32; r0 = (bb / 16) * 32;
  }
  const int tx = threadIdx.x & 31, ty = threadIdx.x >> 5;
  for (int i = ty; i < 32; i += 8) tile[i][tx] = W[(size_t)(r0 + i) * Cc + c0 + tx];
  __syncthreads();
  for (int i = ty; i < 32; i += 8)
    Wt[(size_t)(c0 + i) * R + r0 + tx] = f2bf(tile[tx][i]);
}

// ---------------------------------------------------------------------------
// Kernel A (MFMA): S_c[(h,c)][e][dd] (bf16) = sum_i v[i][e]*kw[i][dd];
// ksum[(h,c)][dd] (fp32). qkv input is bf16.
// ---------------------------------------------------------------------------
__global__ __launch_bounds__(256) void chunk_kv_mfma(
    const short* __restrict__ qkvb, short* __restrict__ Sb, float* __restrict__ ksum) {
  const int c = blockIdx.x, h = blockIdx.y;
  __shared__ short kT[128][72];  // kw^T [dd][i]
  __shared__ short vT[64][72];   // v^T  [e][i]
  const int t = threadIdx.x;
  const int w = t >> 6, lane = t & 63, lr = lane & 15, quad = lane >> 4;

#pragma unroll
  for (int r = 0; r < 16; ++r) {
    const int i = w + 4 * r, d = lane;
    const short* row = qkvb + (size_t)(c * 64 + i) * QKV_W;
    const float kv_ = fmaxf(bf2f(row[E_DIM + h * 64 + d]), 0.f);
    const float v_ = bf2f(row[2 * E_DIM + h * 64 + d]);
    const float th = PI_HALF * (float)(c * 64 + i) / (float)L_SEQ;
    kT[d][i] = f2bf(kv_ * __cosf(th));
    kT[64 + d][i] = f2bf(kv_ * __sinf(th));
    vT[d][i] = f2bf(v_);
  }
  __syncthreads();

  f32x4 acc[8];
#pragma unroll
  for (int n = 0; n < 8; ++n) acc[n] = (f32x4){0.f, 0.f, 0.f, 0.f};
#pragma unroll
  for (int kk = 0; kk < 2; ++kk) {
    const bf16x8 av = *(const bf16x8*)&vT[16 * w + lr][kk * 32 + quad * 8];
#pragma unroll
    for (int n = 0; n < 8; ++n) {
      const bf16x8 bv = *(const bf16x8*)&kT[16 * n + lr][kk * 32 + quad * 8];
      acc[n] = __builtin_amdgcn_mfma_f32_16x16x32_bf16(av, bv, acc[n], 0, 0, 0);
    }
  }

  short* Sc = Sb + ((size_t)(h * NC + c)) * 8192;  // [e][128]
#pragma unroll
  for (int n = 0; n < 8; ++n) {
    const int dd = 16 * n + lr;
#pragma unroll
    for (int r = 0; r < 4; ++r) {
      const int e = 16 * w + quad * 4 + r;
      Sc[(size_t)e * 128 + dd] = f2bf(acc[n][r]);
    }
  }

  if (t < 128) {
    float s = 0.f;
#pragma unroll
    for (int j = 0; j < 8; ++j) {
      const bf16x8 kv8 = *(const bf16x8*)&kT[t][j * 8];
#pragma unroll
      for (int q = 0; q < 8; ++q) s += bf2f(kv8[q]);
    }
    ksum[(size_t)(h * NC + c) * 128 + t] = s;
  }
}

// ---------------------------------------------------------------------------
// Kernel C: per-(chunk, head) output with LINEAR in-register prefix scan.
//   Sp = sum_{c'<c} S_c'   (fp32 regs, 32/thread; S is L2-resident bf16)
//   ctx = Qcat @ Sp^T (one MFMA pass from LDS) + Am @ vT^T (intra)
//   nrm = rowsum(Am) + Qcat . ksumP
// ---------------------------------------------------------------------------
__global__ __launch_bounds__(256) void chunk_out_scan(
    const short* __restrict__ qkvb, const short* __restrict__ Sb,
    const float* __restrict__ ksum, short* __restrict__ attn) {
  const int c = blockIdx.x, h = blockIdx.y;
  __shared__ short Qc[64][136];
  __shared__ short Kc[64][136];
  __shared__ short SpT[64][136];  // Sp tile [e][dd]
  __shared__ short Am[64][72];
  __shared__ short vT[64][72];
  __shared__ float ksumP_s[128];
  __shared__ float nrmP[64][4];
  __shared__ float nrmA[64];
  const int t = threadIdx.x;
  const int w = t >> 6, lane = t & 63, lr = lane & 15, quad = lane >> 4;

  // Linear prefix scan: thread t accumulates elements (t + 256j)*8 .. +7
  float sp[32];
#pragma unroll
  for (int q = 0; q < 32; ++q) sp[q] = 0.f;
  for (int cp = 0; cp < c; ++cp) {
    const short* Sc = Sb + ((size_t)(h * NC + cp)) * 8192;
#pragma unroll
    for (int j = 0; j < 4; ++j) {
      const bf16x8 v8 = *(const bf16x8*)(Sc + (size_t)(t + 256 * j) * 8);
#pragma unroll
      for (int q = 0; q < 8; ++q) sp[j * 8 + q] += bf2f(v8[q]);
    }
  }
#pragma unroll
  for (int j = 0; j < 4; ++j) {
    const int g = t + 256 * j;          // elem group: e = g>>4, dd = (g&15)*8
    bf16x8 o;
#pragma unroll
    for (int q = 0; q < 8; ++q) o[q] = f2bf(sp[j * 8 + q]);
    *(bf16x8*)&SpT[g >> 4][(g & 15) * 8] = o;
  }

  // Load Q/K/V tiles
#pragma unroll
  for (int r = 0; r < 16; ++r) {
    const int i = w + 4 * r, d = lane;
    const short* row = qkvb + (size_t)(c * 64 + i) * QKV_W;
    const float q_ = fmaxf(bf2f(row[h * 64 + d]), 0.f);
    const float k_ = fmaxf(bf2f(row[E_DIM + h * 64 + d]), 0.f);
    const float v_ = bf2f(row[2 * E_DIM + h * 64 + d]);
    const float th = PI_HALF * (float)(c * 64 + i) / (float)L_SEQ;
    const float cw = __cosf(th), sw = __sinf(th);
    Qc[i][d] = f2bf(q_ * cw);
    Qc[i][64 + d] = f2bf(q_ * sw);
    Kc[i][d] = f2bf(k_ * cw);
    Kc[i][64 + d] = f2bf(k_ * sw);
    vT[d][i] = f2bf(v_);
  }
  if (t < 128) {
    float s = 0.f;
    for (int cp = 0; cp < c; ++cp) s += ksum[(size_t)(h * NC + cp) * 128 + t];
    ksumP_s[t] = s;
  }
  __syncthreads();

  // Loop-invariant A-operand fragments of Qcat (row 16w+lr)
  bf16x8 av[4];
#pragma unroll
  for (int kk = 0; kk < 4; ++kk)
    av[kk] = *(const bf16x8*)&Qc[16 * w + lr][kk * 32 + quad * 8];

  // Intra scores: A = Qcat @ Kcat^T
  f32x4 acc_a[4];
#pragma unroll
  for (int n = 0; n < 4; ++n) acc_a[n] = (f32x4){0.f, 0.f, 0.f, 0.f};
#pragma unroll
  for (int kk = 0; kk < 4; ++kk) {
#pragma unroll
    for (int n = 0; n < 4; ++n) {
      const bf16x8 bv = *(const bf16x8*)&Kc[16 * n + lr][kk * 32 + quad * 8];
      acc_a[n] = __builtin_amdgcn_mfma_f32_16x16x32_bf16(av[kk], bv, acc_a[n], 0, 0, 0);
    }
  }
  // Mask, fp32 row-sum via shfl, Am -> LDS bf16
#pragma unroll
  for (int n = 0; n < 4; ++n) {
#pragma unroll
    for (int r = 0; r < 4; ++r) {
      const int gi = 16 * w + quad * 4 + r;
      const int gj = 16 * n + lr;
      float val = (gj <= gi) ? acc_a[n][r] : 0.f;
      Am[gi][gj] = f2bf(val);
      float s = val;
      s += __shfl_xor(s, 1, 64);
      s += __shfl_xor(s, 2, 64);
      s += __shfl_xor(s, 4, 64);
      s += __shfl_xor(s, 8, 64);
      if (lr == 0) nrmP[gi][n] = s;
    }
  }

  // Inter ctx: one MFMA pass over Sp (from LDS)
  f32x4 acc_c[4];
#pragma unroll
  for (int n = 0; n < 4; ++n) acc_c[n] = (f32x4){0.f, 0.f, 0.f, 0.f};
#pragma unroll
  for (int kk = 0; kk < 4; ++kk) {
#pragma unroll
    for (int n = 0; n < 4; ++n) {
      const bf16x8 bv = *(const bf16x8*)&SpT[16 * n + lr][kk * 32 + quad * 8];
      acc_c[n] = __builtin_amdgcn_mfma_f32_16x16x32_bf16(av[kk], bv, acc_c[n], 0, 0, 0);
    }
  }
  __syncthreads();  // Am, nrmP ready

  // Intra ctx: Am @ vT^T
#pragma unroll
  for (int kk = 0; kk < 2; ++kk) {
    const bf16x8 am = *(const bf16x8*)&Am[16 * w + lr][kk * 32 + quad * 8];
#pragma unroll
    for (int n = 0; n < 4; ++n) {
      const bf16x8 bv = *(const bf16x8*)&vT[16 * n + lr][kk * 32 + quad * 8];
      acc_c[n] = __builtin_amdgcn_mfma_f32_16x16x32_bf16(am, bv, acc_c[n], 0, 0, 0);
    }
  }

  // nrm inter-dot: thread (i = t>>2, p = t&3) handles 32 dd
  {
    const int i = t >> 2, p = t & 3;
    float dot = 0.f;
#pragma unroll
    for (int jj = 0; jj < 32; ++jj) {
      const int dd = p * 32 + jj;
      dot += bf2f(Qc[i][dd]) * ksumP_s[dd];
    }
    nrmP[i][p] += dot;
  }
  __syncthreads();
  if (t < 64) nrmA[t] = nrmP[t][0] + nrmP[t][1] + nrmP[t][2] + nrmP[t][3];
  __syncthreads();

#pragma unroll
  for (int n = 0; n < 4; ++n) {
#pragma unroll
    for (int r = 0; r < 4; ++r) {
      const int gi = 16 * w + quad * 4 + r;
      const int e = 16 * n + lr;
      const float val = acc_c[n][r] / (nrmA[gi] + 1e-6f);
      attn[(size_t)(c * 64 + gi) * E_DIM + h * 64 + e] = f2bf(val);
    }
  }
}

// ---------------------------------------------------------------------------
extern "C" void kernel_launch(void* const* d_in, const int* in_sizes, int n_in,
                              void* d_out, int out_size, void* d_ws, size_t ws_size,
                              hipStream_t stream) {
  (void)in_sizes; (void)n_in; (void)out_size; (void)ws_size;
  const float* x     = (const float*)d_in[0];
  const float* W_qkv = (const float*)d_in[1];
  const float* b_qkv = (const float*)d_in[2];
  const float* W_out = (const float*)d_in[3];
  const float* b_out = (const float*)d_in[4];
  float* out = (float*)d_out;

  short* sws = (short*)d_ws;
  short* qkvb   = sws;                     // 3,145,728 bf16
  short* Sb     = qkvb + 3145728;          // 2,097,152 bf16  [hc][e][dd]
  short* attn_b = Sb + 2097152;            // 1,048,576 bf16
  short* xb     = attn_b + 1048576;        // 1,048,576 bf16
  short* Wqkv_t = xb + 1048576;            // 786,432 bf16
  short* Wout_t = Wqkv_t + 786432;         // 262,144 bf16
  float* ksum   = (float*)(Wout_t + 262144);  // 32,768 f32

  // 1) fused prep
  prep_kernel<<<2048, 256, 0, stream>>>(x, W_qkv, W_out, xb, Wqkv_t, Wout_t);

  // 2) qkv = x @ W_qkv + b_qkv -> bf16. 64x64 tiles: 24x32 = 768 blocks (3/CU)
  gemm_mfma_bf16<2, 2, true><<<dim3(QKV_W / 64, L_SEQ / 64), 256, 0, stream>>>(
      xb, Wqkv_t, b_qkv, qkvb, L_SEQ, QKV_W, E_DIM);

  // 3) per-chunk KV sums -> bf16 S, fp32 ksum
  chunk_kv_mfma<<<dim3(NC, H_NUM), 256, 0, stream>>>(qkvb, Sb, ksum);

  // 4) per-chunk outputs with linear register-space scan -> attn bf16
  chunk_out_scan<<<dim3(NC, H_NUM), 256, 0, stream>>>(qkvb, Sb, ksum, attn_b);

  // 5) out = attn @ W_out + b_out -> fp32. 32x64 tiles: 8x64 = 512 blocks (2/CU)
  gemm_mfma_bf16<1, 2, false><<<dim3(E_DIM / 64, L_SEQ / 32), 256, 0, stream>>>(
      attn_b, Wout_t, b_out, out, L_SEQ, E_DIM, E_DIM);
}

// Round 6
// 109.725 us; speedup vs baseline: 1.5177x; 1.0716x over previous
//
#include <hip/hip_runtime.h>

// Problem constants (B=1, L=2048, E=512, H=8, D=64)
constexpr int L_SEQ = 2048;
constexpr int E_DIM = 512;
constexpr int H_NUM = 8;
constexpr int QKV_W = 3 * E_DIM;   // 1536
constexpr int NC = 32;             // 32 chunks of 64
constexpr float PI_HALF = 1.5707963267948966f;

typedef __attribute__((ext_vector_type(8))) short bf16x8;
typedef __attribute__((ext_vector_type(4))) float f32x4;
typedef __attribute__((ext_vector_type(4))) short short4v;

__device__ __forceinline__ short f2bf(float f) {
  union { float f; unsigned int u; } v; v.f = f;
  unsigned int r = v.u + 0x7fffu + ((v.u >> 16) & 1u);  // RNE
  return (short)(r >> 16);
}
__device__ __forceinline__ float bf2f(short s) {
  union { unsigned int u; float f; } v;
  v.u = ((unsigned int)(unsigned short)s) << 16;
  return v.f;
}

__device__ __forceinline__ void glds16(const void* g, void* l) {
  __builtin_amdgcn_global_load_lds(
      (const __attribute__((address_space(1))) unsigned int*)g,
      (__attribute__((address_space(3))) unsigned int*)l, 16, 0, 0);
}

// ---------------------------------------------------------------------------
// bf16 MFMA GEMM: C[M,N] = A[M,K](bf16) @ Bt[N,K](bf16)^T + bias[N]
// OB=true -> C bf16, else C fp32. 256 threads = 4 waves (2x2).
// ---------------------------------------------------------------------------
template <int WTM, int WTN, bool OB>
__global__ __launch_bounds__(256) void gemm_mfma_bf16(
    const short* __restrict__ A, const short* __restrict__ Bt,
    const float* __restrict__ bias, void* __restrict__ Cout,
    int M, int N, int K) {
  constexpr int BM = WTM * 32;
  constexpr int BN = WTN * 32;
  __shared__ short As[BM * 32];
  __shared__ short Bs[BN * 32];

  const int t = threadIdx.x;
  const int wave = t >> 6;
  const int lane = t & 63;
  const int quad = lane >> 4;
  const int lr = lane & 15;

  const int row0 = blockIdx.y * BM;
  const int col0 = blockIdx.x * BN;
  const int wrow = (wave >> 1) * (BM / 2);
  const int wcol = (wave & 1) * (BN / 2);

  f32x4 acc[WTM][WTN];
#pragma unroll
  for (int m = 0; m < WTM; ++m)
#pragma unroll
    for (int n = 0; n < WTN; ++n) acc[m][n] = (f32x4){0.f, 0.f, 0.f, 0.f};

  for (int k0 = 0; k0 < K; k0 += 32) {
#pragma unroll
    for (int p = wave; p < BM / 16; p += 4) {
      const int idx = p * 64 + lane;
      glds16(A + (size_t)(row0 + (idx >> 2)) * K + k0 + (idx & 3) * 8, As + p * 512);
    }
#pragma unroll
    for (int p = wave; p < BN / 16; p += 4) {
      const int idx = p * 64 + lane;
      glds16(Bt + (size_t)(col0 + (idx >> 2)) * K + k0 + (idx & 3) * 8, Bs + p * 512);
    }
    __syncthreads();

    bf16x8 af[WTM], bf_[WTN];
#pragma unroll
    for (int m = 0; m < WTM; ++m)
      af[m] = *(const bf16x8*)(As + (wrow + m * 16 + lr) * 32 + quad * 8);
#pragma unroll
    for (int n = 0; n < WTN; ++n)
      bf_[n] = *(const bf16x8*)(Bs + (wcol + n * 16 + lr) * 32 + quad * 8);
#pragma unroll
    for (int m = 0; m < WTM; ++m)
#pragma unroll
      for (int n = 0; n < WTN; ++n)
        acc[m][n] = __builtin_amdgcn_mfma_f32_16x16x32_bf16(af[m], bf_[n], acc[m][n], 0, 0, 0);
    __syncthreads();
  }

#pragma unroll
  for (int m = 0; m < WTM; ++m) {
#pragma unroll
    for (int n = 0; n < WTN; ++n) {
      const int col = col0 + wcol + n * 16 + lr;
      const int rowb = row0 + wrow + m * 16 + quad * 4;
      const float bb = bias[col];
#pragma unroll
      for (int r = 0; r < 4; ++r) {
        const float val = acc[m][n][r] + bb;
        if (OB)
          ((short*)Cout)[(size_t)(rowb + r) * N + col] = f2bf(val);
        else
          ((float*)Cout)[(size_t)(rowb + r) * N + col] = val;
      }
    }
  }
}

// ---------------------------------------------------------------------------
// Fused prep: cast x -> bf16; transpose-cast W_qkv, W_out -> [N,K] bf16.
// ---------------------------------------------------------------------------
__global__ __launch_bounds__(256) void prep_kernel(
    const float* __restrict__ x, const float* __restrict__ W_qkv,
    const float* __restrict__ W_out, short* __restrict__ xb,
    short* __restrict__ Wqkv_t, short* __restrict__ Wout_t) {
  const int b = blockIdx.x;
  if (b < 1024) {
    const int i = b * 256 + threadIdx.x;
    const float4 v = ((const float4*)x)[i];
    short4v o;
    o.x = f2bf(v.x); o.y = f2bf(v.y); o.z = f2bf(v.z); o.w = f2bf(v.w);
    ((short4v*)xb)[i] = o;
    return;
  }
  __shared__ float tile[32][33];
  const float* W; short* Wt; int R, Cc, c0, r0;
  if (b < 1792) {
    const int bb = b - 1024;
    W = W_qkv; Wt = Wqkv_t; R = E_DIM; Cc = QKV_W;
    c0 = (bb % 48) * 32; r0 = (bb / 48) * 32;
  } else {
    const int bb = b - 1792;
    W = W_out; Wt = Wout_t; R = E_DIM; Cc = E_DIM;
    c0 = (bb % 16) * 32; r0 = (bb / 16) * 32;
  }
  const int tx = threadIdx.x & 31, ty = threadIdx.x >> 5;
  for (int i = ty; i < 32; i += 8) tile[i][tx] = W[(size_t)(r0 + i) * Cc + c0 + tx];
  __syncthreads();
  for (int i = ty; i < 32; i += 8)
    Wt[(size_t)(c0 + i) * R + r0 + tx] = f2bf(tile[tx][i]);
}

// ---------------------------------------------------------------------------
// Kernel A (MFMA): S_c[(h,c)][e][dd] (bf16) = sum_i v[i][e]*kw[i][dd];
// ksum[(h,c)][dd] (fp32). qkv input is bf16.
// ---------------------------------------------------------------------------
__global__ __launch_bounds__(256) void chunk_kv_mfma(
    const short* __restrict__ qkvb, short* __restrict__ Sb, float* __restrict__ ksum) {
  const int c = blockIdx.x, h = blockIdx.y;
  __shared__ short kT[128][72];  // kw^T [dd][i]
  __shared__ short vT[64][72];   // v^T  [e][i]
  const int t = threadIdx.x;
  const int w = t >> 6, lane = t & 63, lr = lane & 15, quad = lane >> 4;

#pragma unroll
  for (int r = 0; r < 16; ++r) {
    const int i = w + 4 * r, d = lane;
    const short* row = qkvb + (size_t)(c * 64 + i) * QKV_W;
    const float kv_ = fmaxf(bf2f(row[E_DIM + h * 64 + d]), 0.f);
    const float v_ = bf2f(row[2 * E_DIM + h * 64 + d]);
    const float th = PI_HALF * (float)(c * 64 + i) / (float)L_SEQ;
    kT[d][i] = f2bf(kv_ * __cosf(th));
    kT[64 + d][i] = f2bf(kv_ * __sinf(th));
    vT[d][i] = f2bf(v_);
  }
  __syncthreads();

  f32x4 acc[8];
#pragma unroll
  for (int n = 0; n < 8; ++n) acc[n] = (f32x4){0.f, 0.f, 0.f, 0.f};
#pragma unroll
  for (int kk = 0; kk < 2; ++kk) {
    const bf16x8 av = *(const bf16x8*)&vT[16 * w + lr][kk * 32 + quad * 8];
#pragma unroll
    for (int n = 0; n < 8; ++n) {
      const bf16x8 bv = *(const bf16x8*)&kT[16 * n + lr][kk * 32 + quad * 8];
      acc[n] = __builtin_amdgcn_mfma_f32_16x16x32_bf16(av, bv, acc[n], 0, 0, 0);
    }
  }

  short* Sc = Sb + ((size_t)(h * NC + c)) * 8192;  // [e][128]
#pragma unroll
  for (int n = 0; n < 8; ++n) {
    const int dd = 16 * n + lr;
#pragma unroll
    for (int r = 0; r < 4; ++r) {
      const int e = 16 * w + quad * 4 + r;
      Sc[(size_t)e * 128 + dd] = f2bf(acc[n][r]);
    }
  }

  if (t < 128) {
    float s = 0.f;
#pragma unroll
    for (int j = 0; j < 8; ++j) {
      const bf16x8 kv8 = *(const bf16x8*)&kT[t][j * 8];
#pragma unroll
      for (int q = 0; q < 8; ++q) s += bf2f(kv8[q]);
    }
    ksum[(size_t)(h * NC + c) * 128 + t] = s;
  }
}

// ---------------------------------------------------------------------------
// Kernel B: balanced exclusive prefix scan over chunks.
// Sb bf16 -> Spb bf16 (fp32 running sum); ksum -> ksumP (fp32).
// Grid (4, 8): every thread streams exactly 32 x 16B loads + 16B stores.
// ---------------------------------------------------------------------------
__global__ __launch_bounds__(256) void scan_kernel(
    const short* __restrict__ Sb, short* __restrict__ Spb,
    const float* __restrict__ ksum, float* __restrict__ ksumP) {
  const int h = blockIdx.y;
  const int g = (blockIdx.x * 256 + threadIdx.x) * 8;  // element offset, 0..8184
  float run[8];
#pragma unroll
  for (int q = 0; q < 8; ++q) run[q] = 0.f;
#pragma unroll
  for (int c = 0; c < NC; ++c) {
    const size_t off = ((size_t)(h * NC + c)) * 8192 + g;
    const bf16x8 v8 = *(const bf16x8*)(Sb + off);
    bf16x8 o;
#pragma unroll
    for (int q = 0; q < 8; ++q) o[q] = f2bf(run[q]);
    *(bf16x8*)(Spb + off) = o;
#pragma unroll
    for (int q = 0; q < 8; ++q) run[q] += bf2f(v8[q]);
  }
  if (blockIdx.x == 0 && threadIdx.x < 128) {
    const int d = threadIdx.x;
    float r2 = 0.f;
#pragma unroll
    for (int c = 0; c < NC; ++c) {
      const size_t off = (size_t)(h * NC + c) * 128 + d;
      ksumP[off] = r2;
      r2 += ksum[off];
    }
  }
}

// ---------------------------------------------------------------------------
// Kernel C (MFMA): per-(chunk, head) output -> attn bf16.
//   ctx = Qcat @ Spb_c^T (B-frags direct from global/L2) + Am @ vT^T
//   nrm = rowsum(Am) + Qcat . ksumP_c
// ---------------------------------------------------------------------------
__global__ __launch_bounds__(256) void chunk_out_mfma(
    const short* __restrict__ qkvb, const short* __restrict__ Spb,
    const float* __restrict__ ksumP, short* __restrict__ attn) {
  const int c = blockIdx.x, h = blockIdx.y;
  __shared__ short Qc[64][136];
  __shared__ short Kc[64][136];
  __shared__ short Am[64][72];
  __shared__ short vT[64][72];
  __shared__ float nrmP[64][4];
  __shared__ float nrmA[64];
  const int t = threadIdx.x;
  const int w = t >> 6, lane = t & 63, lr = lane & 15, quad = lane >> 4;

#pragma unroll
  for (int r = 0; r < 16; ++r) {
    const int i = w + 4 * r, d = lane;
    const short* row = qkvb + (size_t)(c * 64 + i) * QKV_W;
    const float q_ = fmaxf(bf2f(row[h * 64 + d]), 0.f);
    const float k_ = fmaxf(bf2f(row[E_DIM + h * 64 + d]), 0.f);
    const float v_ = bf2f(row[2 * E_DIM + h * 64 + d]);
    const float th = PI_HALF * (float)(c * 64 + i) / (float)L_SEQ;
    const float cw = __cosf(th), sw = __sinf(th);
    Qc[i][d] = f2bf(q_ * cw);
    Qc[i][64 + d] = f2bf(q_ * sw);
    Kc[i][d] = f2bf(k_ * cw);
    Kc[i][64 + d] = f2bf(k_ * sw);
    vT[d][i] = f2bf(v_);
  }
  __syncthreads();

  // Loop-invariant A-operand fragments of Qcat (row 16w+lr)
  bf16x8 av[4];
#pragma unroll
  for (int kk = 0; kk < 4; ++kk)
    av[kk] = *(const bf16x8*)&Qc[16 * w + lr][kk * 32 + quad * 8];

  // Inter ctx: Qcat @ Spb_c^T, B-frags straight from global (L2-resident)
  const short* Spc = Spb + ((size_t)(h * NC + c)) * 8192;  // [e][128]
  f32x4 acc_c[4];
#pragma unroll
  for (int n = 0; n < 4; ++n) acc_c[n] = (f32x4){0.f, 0.f, 0.f, 0.f};
#pragma unroll
  for (int kk = 0; kk < 4; ++kk) {
#pragma unroll
    for (int n = 0; n < 4; ++n) {
      const bf16x8 bv = *(const bf16x8*)(Spc + (size_t)(16 * n + lr) * 128 + kk * 32 + quad * 8);
      acc_c[n] = __builtin_amdgcn_mfma_f32_16x16x32_bf16(av[kk], bv, acc_c[n], 0, 0, 0);
    }
  }

  // Intra scores: A = Qcat @ Kcat^T
  f32x4 acc_a[4];
#pragma unroll
  for (int n = 0; n < 4; ++n) acc_a[n] = (f32x4){0.f, 0.f, 0.f, 0.f};
#pragma unroll
  for (int kk = 0; kk < 4; ++kk) {
#pragma unroll
    for (int n = 0; n < 4; ++n) {
      const bf16x8 bv = *(const bf16x8*)&Kc[16 * n + lr][kk * 32 + quad * 8];
      acc_a[n] = __builtin_amdgcn_mfma_f32_16x16x32_bf16(av[kk], bv, acc_a[n], 0, 0, 0);
    }
  }
  // Mask, fp32 row-sum via shfl, Am -> LDS bf16
#pragma unroll
  for (int n = 0; n < 4; ++n) {
#pragma unroll
    for (int r = 0; r < 4; ++r) {
      const int gi = 16 * w + quad * 4 + r;
      const int gj = 16 * n + lr;
      float val = (gj <= gi) ? acc_a[n][r] : 0.f;
      Am[gi][gj] = f2bf(val);
      float s = val;
      s += __shfl_xor(s, 1, 64);
      s += __shfl_xor(s, 2, 64);
      s += __shfl_xor(s, 4, 64);
      s += __shfl_xor(s, 8, 64);
      if (lr == 0) nrmP[gi][n] = s;
    }
  }
  __syncthreads();  // Am, nrmP ready

  // Intra ctx: Am @ vT^T
#pragma unroll
  for (int kk = 0; kk < 2; ++kk) {
    const bf16x8 am = *(const bf16x8*)&Am[16 * w + lr][kk * 32 + quad * 8];
#pragma unroll
    for (int n = 0; n < 4; ++n) {
      const bf16x8 bv = *(const bf16x8*)&vT[16 * n + lr][kk * 32 + quad * 8];
      acc_c[n] = __builtin_amdgcn_mfma_f32_16x16x32_bf16(am, bv, acc_c[n], 0, 0, 0);
    }
  }

  // nrm inter-dot: thread (i = t>>2, p = t&3) handles 32 dd
  {
    const int i = t >> 2, p = t & 3;
    const float* Kp = ksumP + (size_t)(h * NC + c) * 128;
    float dot = 0.f;
#pragma unroll
    for (int jj = 0; jj < 32; ++jj) {
      const int dd = p * 32 + jj;
      dot += bf2f(Qc[i][dd]) * Kp[dd];
    }
    nrmP[i][p] += dot;
  }
  __syncthreads();
  if (t < 64) nrmA[t] = nrmP[t][0] + nrmP[t][1] + nrmP[t][2] + nrmP[t][3];
  __syncthreads();

#pragma unroll
  for (int n = 0; n < 4; ++n) {
#pragma unroll
    for (int r = 0; r < 4; ++r) {
      const int gi = 16 * w + quad * 4 + r;
      const int e = 16 * n + lr;
      const float val = acc_c[n][r] / (nrmA[gi] + 1e-6f);
      attn[(size_t)(c * 64 + gi) * E_DIM + h * 64 + e] = f2bf(val);
    }
  }
}

// ---------------------------------------------------------------------------
extern "C" void kernel_launch(void* const* d_in, const int* in_sizes, int n_in,
                              void* d_out, int out_size, void* d_ws, size_t ws_size,
                              hipStream_t stream) {
  (void)in_sizes; (void)n_in; (void)out_size; (void)ws_size;
  const float* x     = (const float*)d_in[0];
  const float* W_qkv = (const float*)d_in[1];
  const float* b_qkv = (const float*)d_in[2];
  const float* W_out = (const float*)d_in[3];
  const float* b_out = (const float*)d_in[4];
  float* out = (float*)d_out;

  short* sws = (short*)d_ws;
  short* qkvb   = sws;                     // 3,145,728 bf16
  short* Sb     = qkvb + 3145728;          // 2,097,152 bf16  [hc][e][dd]
  short* Spb    = Sb + 2097152;            // 2,097,152 bf16
  short* attn_b = Spb + 2097152;           // 1,048,576 bf16
  short* xb     = attn_b + 1048576;        // 1,048,576 bf16
  short* Wqkv_t = xb + 1048576;            // 786,432 bf16
  short* Wout_t = Wqkv_t + 786432;         // 262,144 bf16
  float* ksum   = (float*)(Wout_t + 262144);  // 32,768 f32
  float* ksumP  = ksum + 32768;               // 32,768 f32

  // 1) fused prep
  prep_kernel<<<2048, 256, 0, stream>>>(x, W_qkv, W_out, xb, Wqkv_t, Wout_t);

  // 2) qkv = x @ W_qkv + b_qkv -> bf16. 64x64 tiles: 24x32 = 768 blocks (3/CU)
  gemm_mfma_bf16<2, 2, true><<<dim3(QKV_W / 64, L_SEQ / 64), 256, 0, stream>>>(
      xb, Wqkv_t, b_qkv, qkvb, L_SEQ, QKV_W, E_DIM);

  // 3) per-chunk KV sums -> bf16 S, fp32 ksum
  chunk_kv_mfma<<<dim3(NC, H_NUM), 256, 0, stream>>>(qkvb, Sb, ksum);

  // 4) balanced exclusive prefix scan -> bf16 Sp, fp32 ksumP
  scan_kernel<<<dim3(4, H_NUM), 256, 0, stream>>>(Sb, Spb, ksum, ksumP);

  // 5) per-chunk outputs -> attn bf16
  chunk_out_mfma<<<dim3(NC, H_NUM), 256, 0, stream>>>(qkvb, Spb, ksumP, attn_b);

  // 6) out = attn @ W_out + b_out -> fp32. 32x64 tiles: 8x64 = 512 blocks (2/CU)
  gemm_mfma_bf16<1, 2, false><<<dim3(E_DIM / 64, L_SEQ / 32), 256, 0, stream>>>(
      attn_b, Wout_t, b_out, out, L_SEQ, E_DIM, E_DIM);
}